// Round 7
// baseline (438.382 us; speedup 1.0000x reference)
//
#include <hip/hip_runtime.h>
#include <cstdint>

namespace {

typedef __attribute__((ext_vector_type(8))) short bf16x8;
typedef __attribute__((ext_vector_type(4))) short bf16x4;
typedef __attribute__((ext_vector_type(4))) float f32x4;

constexpr int D  = 1024;
constexpr int H  = 16;
constexpr int DH = 64;
constexpr int B  = 2;
constexpr int S  = 2048;
constexpr int M  = B * S;          // 4096

__device__ inline unsigned short f2bf(float f) {
    union { float f; uint32_t u; } v{f};
    return (unsigned short)((v.u + 0x7fffu + ((v.u >> 16) & 1u)) >> 16);
}

__device__ inline void gload16(const void* g, void* l) {
    __builtin_amdgcn_global_load_lds(
        (const __attribute__((address_space(1))) void*)g,
        (__attribute__((address_space(3))) void*)l, 16, 0, 0);
}

// ---------------------------------------------------------------------------
// x [4096,1024] f32 -> bf16
// ---------------------------------------------------------------------------
__global__ __launch_bounds__(256) void pack_x(const float* __restrict__ x,
                                              unsigned short* __restrict__ xb) {
    const int i = (blockIdx.x * 256 + threadIdx.x) * 8;
    float4 a = *reinterpret_cast<const float4*>(&x[i]);
    float4 b = *reinterpret_cast<const float4*>(&x[i + 4]);
    bf16x8 o;
    o[0] = f2bf(a.x); o[1] = f2bf(a.y); o[2] = f2bf(a.z); o[3] = f2bf(a.w);
    o[4] = f2bf(b.x); o[5] = f2bf(b.y); o[6] = f2bf(b.z); o[7] = f2bf(b.w);
    *reinterpret_cast<bf16x8*>(&xb[i]) = o;
}

// ---------------------------------------------------------------------------
// 4 weight matrices [1024 k][1024 n] f32 -> WtAll bf16 [4][n][k]
// ---------------------------------------------------------------------------
__global__ __launch_bounds__(256) void transpose_w4(
    const float* __restrict__ W0, const float* __restrict__ W1,
    const float* __restrict__ W2, const float* __restrict__ W3,
    unsigned short* __restrict__ WtAll)
{
    __shared__ unsigned short T[64][72];
    const int z = blockIdx.z;
    const float* W = z == 0 ? W0 : (z == 1 ? W1 : (z == 2 ? W2 : W3));
    unsigned short* Wt = WtAll + (size_t)z * D * D;
    const int n0 = blockIdx.x * 64, k0 = blockIdx.y * 64;
    const int t = threadIdx.x;
    #pragma unroll
    for (int i = 0; i < 16; ++i) {
        int idx = i * 256 + t, r = idx >> 6, c = idx & 63;
        T[r][c] = f2bf(W[(size_t)(k0 + r) * D + n0 + c]);
    }
    __syncthreads();
    #pragma unroll
    for (int i = 0; i < 16; ++i) {
        int idx = i * 256 + t, r = idx >> 6, c = idx & 63;
        Wt[(size_t)(n0 + r) * D + k0 + c] = T[c][r];
    }
}

// ---------------------------------------------------------------------------
// V [bh][s][dh] bf16 -> Vt [bh][dh][s] bf16
// ---------------------------------------------------------------------------
__global__ __launch_bounds__(256) void transpose_v(const unsigned short* __restrict__ Vb,
                                                   unsigned short* __restrict__ Vt) {
    __shared__ unsigned short T[64][72];
    const int s0 = blockIdx.x * 64, bh = blockIdx.y;
    const unsigned short* src = Vb + (size_t)bh * S * DH;
    unsigned short* dst = Vt + (size_t)bh * DH * S;
    const int t = threadIdx.x;
    #pragma unroll
    for (int i = 0; i < 16; ++i) {
        int idx = i * 256 + t, r = idx >> 6, c = idx & 63;
        T[r][c] = src[(size_t)(s0 + r) * DH + c];
    }
    __syncthreads();
    #pragma unroll
    for (int i = 0; i < 16; ++i) {
        int idx = i * 256 + t, r = idx >> 6, c = idx & 63;
        dst[(size_t)r * S + s0 + c] = T[c][r];
    }
}

// ---------------------------------------------------------------------------
// Fused QKV projection (m97 structure), swapped MFMA -> row-major fragments,
// vector epilogue. 1D grid (768) with bijective XCD swizzle.
// ---------------------------------------------------------------------------
__global__ __launch_bounds__(256) void qkv_gemm(
    const unsigned short* __restrict__ A, const unsigned short* __restrict__ Bt,
    const float* __restrict__ b0, const float* __restrict__ b1,
    const float* __restrict__ b2,
    unsigned short* __restrict__ oQ, unsigned short* __restrict__ oK,
    unsigned short* __restrict__ oV)
{
    __shared__ __align__(16) unsigned short As[128 * 64];
    __shared__ __align__(16) unsigned short Bs[128 * 64];
    const int id = blockIdx.x;
    const int sw = (id & 7) * 96 + (id >> 3);        // 768 blocks, 8 XCDs
    const int m0 = (sw / 24) * 128, n0 = (sw % 24) * 128;
    const int t = threadIdx.x;
    const int lane = t & 63, w = t >> 6;
    const int wr = w >> 1, wc = w & 1;
    const int lo = lane & 15, hi = lane >> 4;

    f32x4 acc[4][4] = {};

    for (int k0 = 0; k0 < D; k0 += 64) {
        #pragma unroll
        for (int i = 0; i < 4; ++i) {
            const int row = i * 32 + w * 8 + (lane >> 3);
            const int gcol = ((lane & 7) * 8) ^ ((row & 7) * 8);  // src pre-swizzle
            gload16(&A[(size_t)(m0 + row) * D + k0 + gcol], &As[i * 2048 + w * 512]);
            gload16(&Bt[(size_t)(n0 + row) * D + k0 + gcol], &Bs[i * 2048 + w * 512]);
        }
        __syncthreads();
        #pragma unroll
        for (int kk = 0; kk < 2; ++kk) {
            bf16x8 a[4], b[4];
            #pragma unroll
            for (int m = 0; m < 4; ++m) {
                const int row = wr * 64 + m * 16 + lo;
                a[m] = *reinterpret_cast<const bf16x8*>(
                    &As[row * 64 + ((kk * 32 + hi * 8) ^ ((row & 7) * 8))]);
            }
            #pragma unroll
            for (int n = 0; n < 4; ++n) {
                const int row = wc * 64 + n * 16 + lo;
                b[n] = *reinterpret_cast<const bf16x8*>(
                    &Bs[row * 64 + ((kk * 32 + hi * 8) ^ ((row & 7) * 8))]);
            }
            #pragma unroll
            for (int m = 0; m < 4; ++m)
                #pragma unroll
                for (int n = 0; n < 4; ++n)
                    acc[m][n] = __builtin_amdgcn_mfma_f32_16x16x32_bf16(b[n], a[m], acc[m][n], 0, 0, 0);
        }
        __syncthreads();
    }

    const int which = n0 >> 10;                 // uniform per block
    const float* bs = which == 0 ? b0 : (which == 1 ? b1 : b2);
    unsigned short* op = which == 0 ? oQ : (which == 1 ? oK : oV);
    const float scale = which == 0 ? 0.125f : 1.0f;
    #pragma unroll
    for (int m = 0; m < 4; ++m) {
        const int row = m0 + wr * 64 + m * 16 + lo;
        const int b_ = row >> 11, s_ = row & (S - 1);
        #pragma unroll
        for (int n = 0; n < 4; ++n) {
            const int nn = (n0 + wc * 64 + n * 16 + hi * 4) & 1023;
            const int h_ = nn >> 6, dh = nn & 63;
            float4 bv = *reinterpret_cast<const float4*>(&bs[nn]);
            bf16x4 o;
            #pragma unroll
            for (int r = 0; r < 4; ++r)
                o[r] = (short)f2bf((acc[m][n][r] + (&bv.x)[r]) * scale);
            *reinterpret_cast<bf16x4*>(
                &op[(((size_t)(b_ * H + h_) * S) + s_) * DH + dh]) = o;
        }
    }
}

// ---------------------------------------------------------------------------
// Output projection: C = ctx[4096,1024] @ Wto^T + bo, fp32 out.
// 1D grid (256) with XCD swizzle; swapped MFMA, nontemporal f32x4 epilogue.
// ---------------------------------------------------------------------------
__global__ __launch_bounds__(256) void out_gemm(
    const unsigned short* __restrict__ A, const unsigned short* __restrict__ Bt,
    const float* __restrict__ bias, float* __restrict__ out)
{
    __shared__ __align__(16) unsigned short As[128 * 64];
    __shared__ __align__(16) unsigned short Bs[128 * 64];
    const int id = blockIdx.x;
    const int sw = (id & 7) * 32 + (id >> 3);        // 256 blocks, 8 XCDs
    const int m0 = (sw >> 3) * 128, n0 = (sw & 7) * 128;
    const int t = threadIdx.x;
    const int lane = t & 63, w = t >> 6;
    const int wr = w >> 1, wc = w & 1;
    const int lo = lane & 15, hi = lane >> 4;

    f32x4 acc[4][4] = {};

    for (int k0 = 0; k0 < D; k0 += 64) {
        #pragma unroll
        for (int i = 0; i < 4; ++i) {
            const int row = i * 32 + w * 8 + (lane >> 3);
            const int gcol = ((lane & 7) * 8) ^ ((row & 7) * 8);
            gload16(&A[(size_t)(m0 + row) * D + k0 + gcol], &As[i * 2048 + w * 512]);
            gload16(&Bt[(size_t)(n0 + row) * D + k0 + gcol], &Bs[i * 2048 + w * 512]);
        }
        __syncthreads();
        #pragma unroll
        for (int kk = 0; kk < 2; ++kk) {
            bf16x8 a[4], b[4];
            #pragma unroll
            for (int m = 0; m < 4; ++m) {
                const int row = wr * 64 + m * 16 + lo;
                a[m] = *reinterpret_cast<const bf16x8*>(
                    &As[row * 64 + ((kk * 32 + hi * 8) ^ ((row & 7) * 8))]);
            }
            #pragma unroll
            for (int n = 0; n < 4; ++n) {
                const int row = wc * 64 + n * 16 + lo;
                b[n] = *reinterpret_cast<const bf16x8*>(
                    &Bs[row * 64 + ((kk * 32 + hi * 8) ^ ((row & 7) * 8))]);
            }
            #pragma unroll
            for (int m = 0; m < 4; ++m)
                #pragma unroll
                for (int n = 0; n < 4; ++n)
                    acc[m][n] = __builtin_amdgcn_mfma_f32_16x16x32_bf16(b[n], a[m], acc[m][n], 0, 0, 0);
        }
        __syncthreads();
    }

    #pragma unroll
    for (int m = 0; m < 4; ++m) {
        const int row = m0 + wr * 64 + m * 16 + lo;
        #pragma unroll
        for (int n = 0; n < 4; ++n) {
            const int colb = n0 + wc * 64 + n * 16 + hi * 4;
            float4 bv = *reinterpret_cast<const float4*>(&bias[colb]);
            f32x4 v;
            #pragma unroll
            for (int r = 0; r < 4; ++r) v[r] = acc[m][n][r] + (&bv.x)[r];
            __builtin_nontemporal_store(
                v, reinterpret_cast<f32x4*>(&out[(size_t)row * D + colb]));
        }
    }
}

// ---------------------------------------------------------------------------
// Pass 1: per-row sumexp (m=0) + zero-fill of the strictly-upper P tiles.
// Swapped QK^T: lane lo owns q-row; 2 shfl_xor reduce. Store traffic
// (268 MB zeros) balances pass 2's 268 MB of values.
// Grid: (qt, bh) — same-bh blocks consecutive for K L2 reuse; heavy-first.
// ---------------------------------------------------------------------------
__global__ __launch_bounds__(256) void attn_stats_zero(
    const unsigned short* __restrict__ Q, const unsigned short* __restrict__ K,
    float* __restrict__ lrow, float* __restrict__ P)
{
    const int qt = (S / 64 - 1) - blockIdx.x;
    const int bh = blockIdx.y;
    const int t = threadIdx.x, lane = t & 63, w = t >> 6;
    const int lo = lane & 15, hi = lane >> 4;
    const int q0 = qt * 64 + w * 16;
    const int myq = q0 + lo;
    const unsigned short* Qb = Q + (size_t)bh * S * DH;
    const unsigned short* Kb = K + (size_t)bh * S * DH;
    float* Pb = P + (size_t)bh * S * S;

    bf16x8 aq[2];
    #pragma unroll
    for (int kk = 0; kk < 2; ++kk)
        aq[kk] = *reinterpret_cast<const bf16x8*>(&Qb[(size_t)myq * DH + kk * 32 + hi * 8]);

    float psum = 0.f;

    for (int jt = 0; jt <= qt; ++jt) {
        f32x4 acc[4] = {};
        #pragma unroll
        for (int kk = 0; kk < 2; ++kk)
            #pragma unroll
            for (int n = 0; n < 4; ++n) {
                bf16x8 bk = *reinterpret_cast<const bf16x8*>(
                    &Kb[(size_t)(jt * 64 + n * 16 + lo) * DH + kk * 32 + hi * 8]);
                acc[n] = __builtin_amdgcn_mfma_f32_16x16x32_bf16(bk, aq[kk], acc[n], 0, 0, 0);
            }
        #pragma unroll
        for (int n = 0; n < 4; ++n)
            #pragma unroll
            for (int r = 0; r < 4; ++r) {
                const int j = jt * 64 + n * 16 + hi * 4 + r;
                psum += (j <= myq) ? __expf(acc[n][r]) : 0.f;
            }
    }
    psum += __shfl_xor(psum, 16);
    psum += __shfl_xor(psum, 32);
    if (lane < 16) lrow[(size_t)bh * S + myq] = 1.0f / psum;

    // zero-fill strictly-upper tiles of P (disjoint from pass-2 writes)
    const f32x4 z = {0.f, 0.f, 0.f, 0.f};
    for (int jt = qt + 1; jt < S / 64; ++jt)
        #pragma unroll
        for (int rr = 0; rr < 4; ++rr) {
            const int qrow = q0 + rr * 4 + hi;
            __builtin_nontemporal_store(
                z, reinterpret_cast<f32x4*>(&Pb[(size_t)qrow * S + jt * 64 + lo * 4]));
        }
}

// ---------------------------------------------------------------------------
// Pass 2: swapped QK^T recompute, p = exp(s)*li staged fp32 in per-wave LDS
// (vector f32x4 writes), coalesced 4-row x 256B nontemporal P-stores, PV
// (swapped) from the same LDS tile, ctx written as bf16x4.
// ---------------------------------------------------------------------------
__global__ __launch_bounds__(256) void attn_probs_ctx(
    const unsigned short* __restrict__ Q, const unsigned short* __restrict__ K,
    const unsigned short* __restrict__ Vt, const float* __restrict__ lrow,
    float* __restrict__ P, unsigned short* __restrict__ ctxb)
{
    __shared__ __align__(16) float Pf[4][16][68];
    const int qt = (S / 64 - 1) - blockIdx.x;
    const int bh = blockIdx.y;
    const int t = threadIdx.x, lane = t & 63, w = t >> 6;
    const int lo = lane & 15, hi = lane >> 4;
    const int q0 = qt * 64 + w * 16;
    const int myq = q0 + lo;
    const unsigned short* Qb = Q + (size_t)bh * S * DH;
    const unsigned short* Kb = K + (size_t)bh * S * DH;
    const unsigned short* Vb = Vt + (size_t)bh * DH * S;
    float* Pb = P + (size_t)bh * S * S;
    float (*pf)[68] = Pf[w];

    bf16x8 aq[2];
    #pragma unroll
    for (int kk = 0; kk < 2; ++kk)
        aq[kk] = *reinterpret_cast<const bf16x8*>(&Qb[(size_t)myq * DH + kk * 32 + hi * 8]);

    const float li = lrow[(size_t)bh * S + myq];

    f32x4 actx[4] = {};

    for (int jt = 0; jt <= qt; ++jt) {
        f32x4 acc[4] = {};
        #pragma unroll
        for (int kk = 0; kk < 2; ++kk)
            #pragma unroll
            for (int n = 0; n < 4; ++n) {
                bf16x8 bk = *reinterpret_cast<const bf16x8*>(
                    &Kb[(size_t)(jt * 64 + n * 16 + lo) * DH + kk * 32 + hi * 8]);
                acc[n] = __builtin_amdgcn_mfma_f32_16x16x32_bf16(bk, aq[kk], acc[n], 0, 0, 0);
            }
        // p = exp(s)*li masked; vector-stage fp32 into per-wave LDS
        #pragma unroll
        for (int n = 0; n < 4; ++n) {
            f32x4 pv4;
            #pragma unroll
            for (int r = 0; r < 4; ++r) {
                const int j = jt * 64 + n * 16 + hi * 4 + r;
                pv4[r] = (j <= myq) ? __expf(acc[n][r]) * li : 0.f;
            }
            *reinterpret_cast<f32x4*>(&pf[lo][n * 16 + hi * 4]) = pv4;
        }
        // coalesced nontemporal stores: 4 rows x 256B per instruction
        #pragma unroll
        for (int i2 = 0; i2 < 4; ++i2) {
            f32x4 v = *reinterpret_cast<const f32x4*>(&pf[i2 * 4 + hi][lo * 4]);
            __builtin_nontemporal_store(
                v, reinterpret_cast<f32x4*>(&Pb[(size_t)(q0 + i2 * 4 + hi) * S + jt * 64 + lo * 4]));
        }
        // PV (swapped): pa rows = q (lane-local row myq), bv rows = dh
        #pragma unroll
        for (int kk = 0; kk < 2; ++kk) {
            const float* src = &pf[lo][kk * 32 + hi * 8];
            float4 f0 = *reinterpret_cast<const float4*>(src);
            float4 f1 = *reinterpret_cast<const float4*>(src + 4);
            bf16x8 pa;
            pa[0] = f2bf(f0.x); pa[1] = f2bf(f0.y); pa[2] = f2bf(f0.z); pa[3] = f2bf(f0.w);
            pa[4] = f2bf(f1.x); pa[5] = f2bf(f1.y); pa[6] = f2bf(f1.z); pa[7] = f2bf(f1.w);
            #pragma unroll
            for (int n2 = 0; n2 < 4; ++n2) {
                bf16x8 bv = *reinterpret_cast<const bf16x8*>(
                    &Vb[(size_t)(n2 * 16 + lo) * S + jt * 64 + kk * 32 + hi * 8]);
                actx[n2] = __builtin_amdgcn_mfma_f32_16x16x32_bf16(bv, pa, actx[n2], 0, 0, 0);
            }
        }
    }

    // ctx -> merged-head bf16 [b*S+q][h*64+dh]; lane owns row myq, 4 cols
    const int b_ = bh >> 4, h_ = bh & 15;
    #pragma unroll
    for (int n2 = 0; n2 < 4; ++n2) {
        bf16x4 o;
        #pragma unroll
        for (int r = 0; r < 4; ++r) o[r] = (short)f2bf(actx[n2][r]);
        *reinterpret_cast<bf16x4*>(
            &ctxb[((size_t)(b_ * S + myq)) * D + h_ * 64 + n2 * 16 + hi * 4]) = o;
    }
}

}  // namespace

extern "C" void kernel_launch(void* const* d_in, const int* in_sizes, int n_in,
                              void* d_out, int out_size, void* d_ws, size_t ws_size,
                              hipStream_t stream) {
    const float* x  = (const float*)d_in[0];
    const float* Wq = (const float*)d_in[2];
    const float* bq = (const float*)d_in[3];
    const float* Wk = (const float*)d_in[4];
    const float* bk = (const float*)d_in[5];
    const float* Wv = (const float*)d_in[6];
    const float* bv = (const float*)d_in[7];
    const float* Wo = (const float*)d_in[8];
    const float* bo = (const float*)d_in[9];

    float* out = (float*)d_out;
    float* P   = out + (size_t)M * D;

    char* ws = (char*)d_ws;
    const size_t MB = 1u << 20;
    unsigned short* xb    = (unsigned short*)(ws);            // 8 MB
    unsigned short* WtAll = (unsigned short*)(ws + 8 * MB);   // 8 MB  [Wq|Wk|Wv|Wo] transposed
    unsigned short* Qb    = (unsigned short*)(ws + 16 * MB);  // 8 MB
    unsigned short* Kb    = (unsigned short*)(ws + 24 * MB);  // 8 MB
    unsigned short* Vtmp  = (unsigned short*)(ws + 32 * MB);  // 8 MB
    unsigned short* Vtb   = (unsigned short*)(ws + 40 * MB);  // 8 MB
    unsigned short* ctxb  = (unsigned short*)(ws + 48 * MB);  // 8 MB
    float* lrow           = (float*)(ws + 56 * MB);           // 256 KB

    const dim3 blk(256);

    pack_x<<<dim3(M * D / (256 * 8)), blk, 0, stream>>>(x, xb);
    transpose_w4<<<dim3(16, 16, 4), blk, 0, stream>>>(Wq, Wk, Wv, Wo, WtAll);

    // fused QKV projection: N = 3072
    qkv_gemm<<<dim3(768), blk, 0, stream>>>(xb, WtAll, bq, bk, bv, Qb, Kb, Vtmp);
    transpose_v<<<dim3(S / 64, B * H), blk, 0, stream>>>(Vtmp, Vtb);

    // pass 1: rowsum + upper-triangle zero-fill
    attn_stats_zero<<<dim3(S / 64, B * H), blk, 0, stream>>>(Qb, Kb, lrow, P);

    // pass 2: P values + PV context
    attn_probs_ctx<<<dim3(S / 64, B * H), blk, 0, stream>>>(Qb, Kb, Vtb, lrow, P, ctxb);

    // output projection
    out_gemm<<<dim3(256), blk, 0, stream>>>(ctxb, WtAll + (size_t)3 * D * D, bo, out);
}

// Round 8
// 320.116 us; speedup vs baseline: 1.3694x; 1.3694x over previous
//
#include <hip/hip_runtime.h>
#include <cstdint>

namespace {

typedef __attribute__((ext_vector_type(8))) short bf16x8;
typedef __attribute__((ext_vector_type(4))) short bf16x4;
typedef __attribute__((ext_vector_type(4))) float f32x4;

constexpr int D  = 1024;
constexpr int H  = 16;
constexpr int DH = 64;
constexpr int B  = 2;
constexpr int S  = 2048;
constexpr int M  = B * S;          // 4096

__device__ inline unsigned short f2bf(float f) {
    union { float f; uint32_t u; } v{f};
    return (unsigned short)((v.u + 0x7fffu + ((v.u >> 16) & 1u)) >> 16);
}

__device__ inline void gload16(const void* g, void* l) {
    __builtin_amdgcn_global_load_lds(
        (const __attribute__((address_space(1))) void*)g,
        (__attribute__((address_space(3))) void*)l, 16, 0, 0);
}

// ---------------------------------------------------------------------------
// x [4096,1024] f32 -> bf16
// ---------------------------------------------------------------------------
__global__ __launch_bounds__(256) void pack_x(const float* __restrict__ x,
                                              unsigned short* __restrict__ xb) {
    const int i = (blockIdx.x * 256 + threadIdx.x) * 8;
    float4 a = *reinterpret_cast<const float4*>(&x[i]);
    float4 b = *reinterpret_cast<const float4*>(&x[i + 4]);
    bf16x8 o;
    o[0] = f2bf(a.x); o[1] = f2bf(a.y); o[2] = f2bf(a.z); o[3] = f2bf(a.w);
    o[4] = f2bf(b.x); o[5] = f2bf(b.y); o[6] = f2bf(b.z); o[7] = f2bf(b.w);
    *reinterpret_cast<bf16x8*>(&xb[i]) = o;
}

// ---------------------------------------------------------------------------
// 4 weight matrices [1024 k][1024 n] f32 -> WtAll bf16 [4][n][k]
// ---------------------------------------------------------------------------
__global__ __launch_bounds__(256) void transpose_w4(
    const float* __restrict__ W0, const float* __restrict__ W1,
    const float* __restrict__ W2, const float* __restrict__ W3,
    unsigned short* __restrict__ WtAll)
{
    __shared__ unsigned short T[64][72];
    const int z = blockIdx.z;
    const float* W = z == 0 ? W0 : (z == 1 ? W1 : (z == 2 ? W2 : W3));
    unsigned short* Wt = WtAll + (size_t)z * D * D;
    const int n0 = blockIdx.x * 64, k0 = blockIdx.y * 64;
    const int t = threadIdx.x;
    #pragma unroll
    for (int i = 0; i < 16; ++i) {
        int idx = i * 256 + t, r = idx >> 6, c = idx & 63;
        T[r][c] = f2bf(W[(size_t)(k0 + r) * D + n0 + c]);
    }
    __syncthreads();
    #pragma unroll
    for (int i = 0; i < 16; ++i) {
        int idx = i * 256 + t, r = idx >> 6, c = idx & 63;
        Wt[(size_t)(n0 + r) * D + k0 + c] = T[c][r];
    }
}

// ---------------------------------------------------------------------------
// MFMA GEMM, m97 structure: global_load_lds(16B) + XOR-swizzled linear LDS.
// C[M,N] = A[M,K] @ Bt[N,K]^T + bias.  128x128 tile, BK=64, 4 waves (2x2).
// MODE 0: fused QKV (N=3072): Q (scaled 0.125), K -> split-head bf16;
//         V -> Vt[bh][dh][s] bf16 DIRECTLY (transpose folded into epilogue).
// MODE 1: fp32 row-major out (final projection, N=1024).
// ---------------------------------------------------------------------------
template <int MODE>
__global__ __launch_bounds__(256) void mfma_gemm(
    const unsigned short* __restrict__ A, const unsigned short* __restrict__ Bt,
    const float* __restrict__ b0, const float* __restrict__ b1,
    const float* __restrict__ b2,
    unsigned short* __restrict__ oQ, unsigned short* __restrict__ oK,
    unsigned short* __restrict__ oVt, float* __restrict__ oF)
{
    __shared__ __align__(16) unsigned short As[128 * 64];
    __shared__ __align__(16) unsigned short Bs[128 * 64];
    const int t = threadIdx.x;
    const int lane = t & 63, w = t >> 6;
    const int wr = w >> 1, wc = w & 1;
    const int lo = lane & 15, hi = lane >> 4;
    const int m0 = blockIdx.y * 128, n0 = blockIdx.x * 128;

    f32x4 acc[4][4] = {};

    for (int k0 = 0; k0 < D; k0 += 64) {
        #pragma unroll
        for (int i = 0; i < 4; ++i) {
            const int row = i * 32 + w * 8 + (lane >> 3);
            const int gcol = ((lane & 7) * 8) ^ ((row & 7) * 8);  // src pre-swizzle
            gload16(&A[(size_t)(m0 + row) * D + k0 + gcol], &As[i * 2048 + w * 512]);
            gload16(&Bt[(size_t)(n0 + row) * D + k0 + gcol], &Bs[i * 2048 + w * 512]);
        }
        __syncthreads();
        #pragma unroll
        for (int kk = 0; kk < 2; ++kk) {
            bf16x8 a[4], b[4];
            #pragma unroll
            for (int m = 0; m < 4; ++m) {
                const int row = wr * 64 + m * 16 + lo;
                a[m] = *reinterpret_cast<const bf16x8*>(
                    &As[row * 64 + ((kk * 32 + hi * 8) ^ ((row & 7) * 8))]);
            }
            #pragma unroll
            for (int n = 0; n < 4; ++n) {
                const int row = wc * 64 + n * 16 + lo;
                b[n] = *reinterpret_cast<const bf16x8*>(
                    &Bs[row * 64 + ((kk * 32 + hi * 8) ^ ((row & 7) * 8))]);
            }
            #pragma unroll
            for (int m = 0; m < 4; ++m)
                #pragma unroll
                for (int n = 0; n < 4; ++n)
                    acc[m][n] = __builtin_amdgcn_mfma_f32_16x16x32_bf16(a[m], b[n], acc[m][n], 0, 0, 0);
        }
        __syncthreads();
    }

    // acc[m][n][r]: row = m0+wr*64+m*16+hi*4+r, col = n0+wc*64+n*16+lo
    if (MODE == 0) {
        const int which = n0 >> 10;                 // uniform per block
        if (which == 2) {
            // V: write Vt[bh][dh][s] directly; 4 consecutive s per lane -> bf16x4
            #pragma unroll
            for (int m = 0; m < 4; ++m) {
                const int row0 = m0 + wr * 64 + m * 16 + hi * 4;
                const int b_ = row0 >> 11, s_ = row0 & (S - 1);
                #pragma unroll
                for (int n = 0; n < 4; ++n) {
                    const int nn = (n0 + wc * 64 + n * 16 + lo) & 1023;
                    const int h_ = nn >> 6, dh = nn & 63;
                    const float bcol = b2[nn];
                    bf16x4 o;
                    #pragma unroll
                    for (int r = 0; r < 4; ++r) o[r] = (short)f2bf(acc[m][n][r] + bcol);
                    *reinterpret_cast<bf16x4*>(
                        &oVt[((size_t)(b_ * H + h_) * DH + dh) * S + s_]) = o;
                }
            }
        } else {
            const float* bs = which == 0 ? b0 : b1;
            unsigned short* op = which == 0 ? oQ : oK;
            const float scale = which == 0 ? 0.125f : 1.0f;
            #pragma unroll
            for (int m = 0; m < 4; ++m)
                #pragma unroll
                for (int n = 0; n < 4; ++n) {
                    const int nn = (n0 + wc * 64 + n * 16 + lo) & 1023;
                    const float bcol = bs[nn];
                    const int h_ = nn >> 6, dh = nn & 63;
                    #pragma unroll
                    for (int r = 0; r < 4; ++r) {
                        const int row = m0 + wr * 64 + m * 16 + hi * 4 + r;
                        const int b_ = row >> 11, s_ = row & (S - 1);
                        op[(((size_t)(b_ * H + h_) * S) + s_) * DH + dh] =
                            f2bf((acc[m][n][r] + bcol) * scale);
                    }
                }
        }
    } else {
        #pragma unroll
        for (int m = 0; m < 4; ++m)
            #pragma unroll
            for (int n = 0; n < 4; ++n) {
                const int col = n0 + wc * 64 + n * 16 + lo;
                const float bcol = b0[col];
                #pragma unroll
                for (int r = 0; r < 4; ++r) {
                    const int row = m0 + wr * 64 + m * 16 + hi * 4 + r;
                    oF[(size_t)row * D + col] = acc[m][n][r] + bcol;
                }
            }
    }
}

// ---------------------------------------------------------------------------
// Pass 1: per-row sumexp (m=0: logits are O(10), exp never overflows fp32).
// Stores 1/sum.  Heavy tiles first: qt = 31 - blockIdx.y, bh fastest.
// ---------------------------------------------------------------------------
__global__ __launch_bounds__(256) void attn_stats(
    const unsigned short* __restrict__ Q, const unsigned short* __restrict__ K,
    float* __restrict__ lrow)
{
    const int bh = blockIdx.x;
    const int qt = (S / 64 - 1) - blockIdx.y;
    const int t = threadIdx.x, lane = t & 63, w = t >> 6;
    const int lo = lane & 15, hi = lane >> 4;
    const int q0 = qt * 64 + w * 16;
    const unsigned short* Qb = Q + (size_t)bh * S * DH;
    const unsigned short* Kb = K + (size_t)bh * S * DH;

    bf16x8 aq[2];
    #pragma unroll
    for (int kk = 0; kk < 2; ++kk)
        aq[kk] = *reinterpret_cast<const bf16x8*>(&Qb[(size_t)(q0 + lo) * DH + kk * 32 + hi * 8]);

    float rsum[4] = {0.f, 0.f, 0.f, 0.f};

    for (int jt = 0; jt <= qt; ++jt) {
        f32x4 acc[4] = {};
        #pragma unroll
        for (int kk = 0; kk < 2; ++kk)
            #pragma unroll
            for (int n = 0; n < 4; ++n) {
                bf16x8 bk = *reinterpret_cast<const bf16x8*>(
                    &Kb[(size_t)(jt * 64 + n * 16 + lo) * DH + kk * 32 + hi * 8]);
                acc[n] = __builtin_amdgcn_mfma_f32_16x16x32_bf16(aq[kk], bk, acc[n], 0, 0, 0);
            }
        const bool diag = (jt == qt);
        #pragma unroll
        for (int n = 0; n < 4; ++n) {
            const int j = jt * 64 + n * 16 + lo;
            #pragma unroll
            for (int r = 0; r < 4; ++r) {
                const float e = __expf(acc[n][r]);
                rsum[r] += (diag && j > q0 + hi * 4 + r) ? 0.f : e;
            }
        }
    }
    #pragma unroll
    for (int r = 0; r < 4; ++r) {
        #pragma unroll
        for (int off = 1; off < 16; off <<= 1) rsum[r] += __shfl_xor(rsum[r], off);
    }
    if (lo == 0) {
        #pragma unroll
        for (int r = 0; r < 4; ++r)
            lrow[(size_t)bh * S + q0 + hi * 4 + r] = 1.0f / rsum[r];
    }
}

// ---------------------------------------------------------------------------
// Pass 2: recompute QK^T, p = exp(s)*li; stage fp32 in per-wave LDS
// (double-buffered over jt to break the WAR chain); write P with coalesced
// 4-row x 256B nontemporal f32x4 stores; build PV A-frags from the same tile.
// ---------------------------------------------------------------------------
__global__ __launch_bounds__(256) void attn_probs_ctx(
    const unsigned short* __restrict__ Q, const unsigned short* __restrict__ K,
    const unsigned short* __restrict__ Vt, const float* __restrict__ lrow,
    float* __restrict__ P, unsigned short* __restrict__ ctxb)
{
    __shared__ __align__(16) float Pf[2][4][16][68];
    const int bh = blockIdx.x;
    const int qt = (S / 64 - 1) - blockIdx.y;
    const int t = threadIdx.x, lane = t & 63, w = t >> 6;
    const int lo = lane & 15, hi = lane >> 4;
    const int q0 = qt * 64 + w * 16;
    const unsigned short* Qb = Q + (size_t)bh * S * DH;
    const unsigned short* Kb = K + (size_t)bh * S * DH;
    const unsigned short* Vb = Vt + (size_t)bh * DH * S;
    float* Pb = P + (size_t)bh * S * S;

    bf16x8 aq[2];
    #pragma unroll
    for (int kk = 0; kk < 2; ++kk)
        aq[kk] = *reinterpret_cast<const bf16x8*>(&Qb[(size_t)(q0 + lo) * DH + kk * 32 + hi * 8]);

    float li[4];
    #pragma unroll
    for (int r = 0; r < 4; ++r) li[r] = lrow[(size_t)bh * S + q0 + hi * 4 + r];

    f32x4 actx[4] = {};

    for (int jt = 0; jt <= qt; ++jt) {
        float (*pf)[68] = Pf[jt & 1][w];
        f32x4 acc[4] = {};
        #pragma unroll
        for (int kk = 0; kk < 2; ++kk)
            #pragma unroll
            for (int n = 0; n < 4; ++n) {
                bf16x8 bk = *reinterpret_cast<const bf16x8*>(
                    &Kb[(size_t)(jt * 64 + n * 16 + lo) * DH + kk * 32 + hi * 8]);
                acc[n] = __builtin_amdgcn_mfma_f32_16x16x32_bf16(aq[kk], bk, acc[n], 0, 0, 0);
            }
        const bool diag = (jt == qt);
        #pragma unroll
        for (int n = 0; n < 4; ++n) {
            const int j = jt * 64 + n * 16 + lo;
            #pragma unroll
            for (int r = 0; r < 4; ++r) {
                const int qrow = q0 + hi * 4 + r;
                float p = __expf(acc[n][r]) * li[r];
                p = (diag && j > qrow) ? 0.f : p;
                pf[hi * 4 + r][n * 16 + lo] = p;
            }
        }
        // coalesced nontemporal f32x4 stores of the 16x64 fp32 tile
        #pragma unroll
        for (int i2 = 0; i2 < 4; ++i2) {
            const int row = i2 * 4 + hi;
            f32x4 v = *reinterpret_cast<const f32x4*>(&pf[row][lo * 4]);
            __builtin_nontemporal_store(
                v, reinterpret_cast<f32x4*>(&Pb[(size_t)(q0 + row) * S + jt * 64 + lo * 4]));
        }
        // PV: A-frag rebuilt from LDS fp32 (row=lo, k=kk*32+hi*8..+8)
        #pragma unroll
        for (int kk = 0; kk < 2; ++kk) {
            const float* src = &pf[lo][kk * 32 + hi * 8];
            float4 f0 = *reinterpret_cast<const float4*>(src);
            float4 f1 = *reinterpret_cast<const float4*>(src + 4);
            bf16x8 pa;
            pa[0] = f2bf(f0.x); pa[1] = f2bf(f0.y); pa[2] = f2bf(f0.z); pa[3] = f2bf(f0.w);
            pa[4] = f2bf(f1.x); pa[5] = f2bf(f1.y); pa[6] = f2bf(f1.z); pa[7] = f2bf(f1.w);
            #pragma unroll
            for (int n2 = 0; n2 < 4; ++n2) {
                bf16x8 bv = *reinterpret_cast<const bf16x8*>(
                    &Vb[(size_t)(n2 * 16 + lo) * S + jt * 64 + kk * 32 + hi * 8]);
                actx[n2] = __builtin_amdgcn_mfma_f32_16x16x32_bf16(pa, bv, actx[n2], 0, 0, 0);
            }
        }
    }

    // zero-fill strictly-upper tiles of P
    const f32x4 z = {0.f, 0.f, 0.f, 0.f};
    for (int jt = qt + 1; jt < S / 64; ++jt)
        #pragma unroll
        for (int rr = 0; rr < 4; ++rr) {
            const int qrow = q0 + rr * 4 + hi;
            __builtin_nontemporal_store(
                z, reinterpret_cast<f32x4*>(&Pb[(size_t)qrow * S + jt * 64 + lo * 4]));
        }

    // ctx -> merged-head bf16 [b*S+q][h*64+dh]
    const int b_ = bh >> 4, h_ = bh & 15;
    #pragma unroll
    for (int n2 = 0; n2 < 4; ++n2)
        #pragma unroll
        for (int r = 0; r < 4; ++r) {
            const int qg = q0 + hi * 4 + r;
            ctxb[((size_t)(b_ * S + qg)) * D + h_ * 64 + n2 * 16 + lo] = f2bf(actx[n2][r]);
        }
}

}  // namespace

extern "C" void kernel_launch(void* const* d_in, const int* in_sizes, int n_in,
                              void* d_out, int out_size, void* d_ws, size_t ws_size,
                              hipStream_t stream) {
    const float* x  = (const float*)d_in[0];
    const float* Wq = (const float*)d_in[2];
    const float* bq = (const float*)d_in[3];
    const float* Wk = (const float*)d_in[4];
    const float* bk = (const float*)d_in[5];
    const float* Wv = (const float*)d_in[6];
    const float* bv = (const float*)d_in[7];
    const float* Wo = (const float*)d_in[8];
    const float* bo = (const float*)d_in[9];

    float* out = (float*)d_out;
    float* P   = out + (size_t)M * D;

    char* ws = (char*)d_ws;
    const size_t MB = 1u << 20;
    unsigned short* xb    = (unsigned short*)(ws);            // 8 MB
    unsigned short* WtAll = (unsigned short*)(ws + 8 * MB);   // 8 MB  [Wq|Wk|Wv|Wo] transposed
    unsigned short* Qb    = (unsigned short*)(ws + 16 * MB);  // 8 MB
    unsigned short* Kb    = (unsigned short*)(ws + 24 * MB);  // 8 MB
    unsigned short* Vtb   = (unsigned short*)(ws + 32 * MB);  // 8 MB  [bh][dh][s]
    unsigned short* ctxb  = (unsigned short*)(ws + 40 * MB);  // 8 MB
    float* lrow           = (float*)(ws + 48 * MB);           // 256 KB

    const dim3 blk(256);

    pack_x<<<dim3(M * D / (256 * 8)), blk, 0, stream>>>(x, xb);
    transpose_w4<<<dim3(16, 16, 4), blk, 0, stream>>>(Wq, Wk, Wv, Wo, WtAll);

    // fused QKV projection: N = 3072; V written directly transposed
    mfma_gemm<0><<<dim3(24, M / 128), blk, 0, stream>>>(
        xb, WtAll, bq, bk, bv, Qb, Kb, Vtb, nullptr);

    attn_stats<<<dim3(B * H, S / 64), blk, 0, stream>>>(Qb, Kb, lrow);
    attn_probs_ctx<<<dim3(B * H, S / 64), blk, 0, stream>>>(Qb, Kb, Vtb, lrow, P, ctxb);

    // output projection
    mfma_gemm<1><<<dim3(8, M / 128), blk, 0, stream>>>(
        ctxb, WtAll + (size_t)3 * D * D, bo, nullptr, nullptr,
        nullptr, nullptr, nullptr, out);
}

// Round 9
// 312.834 us; speedup vs baseline: 1.4013x; 1.0233x over previous
//
#include <hip/hip_runtime.h>
#include <cstdint>

namespace {

typedef __attribute__((ext_vector_type(8))) short bf16x8;
typedef __attribute__((ext_vector_type(4))) short bf16x4;
typedef __attribute__((ext_vector_type(4))) float f32x4;

constexpr int D  = 1024;
constexpr int H  = 16;
constexpr int DH = 64;
constexpr int B  = 2;
constexpr int S  = 2048;
constexpr int M  = B * S;          // 4096

__device__ inline unsigned short f2bf(float f) {
    union { float f; uint32_t u; } v{f};
    return (unsigned short)((v.u + 0x7fffu + ((v.u >> 16) & 1u)) >> 16);
}

__device__ inline void gload16(const void* g, void* l) {
    __builtin_amdgcn_global_load_lds(
        (const __attribute__((address_space(1))) void*)g,
        (__attribute__((address_space(3))) void*)l, 16, 0, 0);
}

// ---------------------------------------------------------------------------
// x [4096,1024] f32 -> bf16
// ---------------------------------------------------------------------------
__global__ __launch_bounds__(256) void pack_x(const float* __restrict__ x,
                                              unsigned short* __restrict__ xb) {
    const int i = (blockIdx.x * 256 + threadIdx.x) * 8;
    float4 a = *reinterpret_cast<const float4*>(&x[i]);
    float4 b = *reinterpret_cast<const float4*>(&x[i + 4]);
    bf16x8 o;
    o[0] = f2bf(a.x); o[1] = f2bf(a.y); o[2] = f2bf(a.z); o[3] = f2bf(a.w);
    o[4] = f2bf(b.x); o[5] = f2bf(b.y); o[6] = f2bf(b.z); o[7] = f2bf(b.w);
    *reinterpret_cast<bf16x8*>(&xb[i]) = o;
}

// ---------------------------------------------------------------------------
// 4 weight matrices [1024 k][1024 n] f32 -> WtAll bf16 [4][n][k]
// ---------------------------------------------------------------------------
__global__ __launch_bounds__(256) void transpose_w4(
    const float* __restrict__ W0, const float* __restrict__ W1,
    const float* __restrict__ W2, const float* __restrict__ W3,
    unsigned short* __restrict__ WtAll)
{
    __shared__ unsigned short T[64][72];
    const int z = blockIdx.z;
    const float* W = z == 0 ? W0 : (z == 1 ? W1 : (z == 2 ? W2 : W3));
    unsigned short* Wt = WtAll + (size_t)z * D * D;
    const int n0 = blockIdx.x * 64, k0 = blockIdx.y * 64;
    const int t = threadIdx.x;
    #pragma unroll
    for (int i = 0; i < 16; ++i) {
        int idx = i * 256 + t, r = idx >> 6, c = idx & 63;
        T[r][c] = f2bf(W[(size_t)(k0 + r) * D + n0 + c]);
    }
    __syncthreads();
    #pragma unroll
    for (int i = 0; i < 16; ++i) {
        int idx = i * 256 + t, r = idx >> 6, c = idx & 63;
        Wt[(size_t)(n0 + r) * D + k0 + c] = T[c][r];
    }
}

// ---------------------------------------------------------------------------
// MFMA GEMM, m97 structure: global_load_lds(16B) + XOR-swizzled linear LDS.
// C[M,N] = A[M,K] @ Bt[N,K]^T + bias.  128x128 tile, BK=64, 4 waves (2x2).
// MODE 0: fused QKV (N=3072): Q (scaled 0.125), K -> split-head bf16;
//         V -> Vt[bh][dh][s] bf16 DIRECTLY (transpose folded into epilogue).
// MODE 1: fp32 row-major out (final projection, N=1024).
// ---------------------------------------------------------------------------
template <int MODE>
__global__ __launch_bounds__(256) void mfma_gemm(
    const unsigned short* __restrict__ A, const unsigned short* __restrict__ Bt,
    const float* __restrict__ b0, const float* __restrict__ b1,
    const float* __restrict__ b2,
    unsigned short* __restrict__ oQ, unsigned short* __restrict__ oK,
    unsigned short* __restrict__ oVt, float* __restrict__ oF)
{
    __shared__ __align__(16) unsigned short As[128 * 64];
    __shared__ __align__(16) unsigned short Bs[128 * 64];
    const int t = threadIdx.x;
    const int lane = t & 63, w = t >> 6;
    const int wr = w >> 1, wc = w & 1;
    const int lo = lane & 15, hi = lane >> 4;
    const int m0 = blockIdx.y * 128, n0 = blockIdx.x * 128;

    f32x4 acc[4][4] = {};

    for (int k0 = 0; k0 < D; k0 += 64) {
        #pragma unroll
        for (int i = 0; i < 4; ++i) {
            const int row = i * 32 + w * 8 + (lane >> 3);
            const int gcol = ((lane & 7) * 8) ^ ((row & 7) * 8);  // src pre-swizzle
            gload16(&A[(size_t)(m0 + row) * D + k0 + gcol], &As[i * 2048 + w * 512]);
            gload16(&Bt[(size_t)(n0 + row) * D + k0 + gcol], &Bs[i * 2048 + w * 512]);
        }
        __syncthreads();
        #pragma unroll
        for (int kk = 0; kk < 2; ++kk) {
            bf16x8 a[4], b[4];
            #pragma unroll
            for (int m = 0; m < 4; ++m) {
                const int row = wr * 64 + m * 16 + lo;
                a[m] = *reinterpret_cast<const bf16x8*>(
                    &As[row * 64 + ((kk * 32 + hi * 8) ^ ((row & 7) * 8))]);
            }
            #pragma unroll
            for (int n = 0; n < 4; ++n) {
                const int row = wc * 64 + n * 16 + lo;
                b[n] = *reinterpret_cast<const bf16x8*>(
                    &Bs[row * 64 + ((kk * 32 + hi * 8) ^ ((row & 7) * 8))]);
            }
            #pragma unroll
            for (int m = 0; m < 4; ++m)
                #pragma unroll
                for (int n = 0; n < 4; ++n)
                    acc[m][n] = __builtin_amdgcn_mfma_f32_16x16x32_bf16(a[m], b[n], acc[m][n], 0, 0, 0);
        }
        __syncthreads();
    }

    // acc[m][n][r]: row = m0+wr*64+m*16+hi*4+r, col = n0+wc*64+n*16+lo
    if (MODE == 0) {
        const int which = n0 >> 10;                 // uniform per block
        if (which == 2) {
            // V: write Vt[bh][dh][s] directly; 4 consecutive s per lane -> bf16x4
            #pragma unroll
            for (int m = 0; m < 4; ++m) {
                const int row0 = m0 + wr * 64 + m * 16 + hi * 4;
                const int b_ = row0 >> 11, s_ = row0 & (S - 1);
                #pragma unroll
                for (int n = 0; n < 4; ++n) {
                    const int nn = (n0 + wc * 64 + n * 16 + lo) & 1023;
                    const int h_ = nn >> 6, dh = nn & 63;
                    const float bcol = b2[nn];
                    bf16x4 o;
                    #pragma unroll
                    for (int r = 0; r < 4; ++r) o[r] = (short)f2bf(acc[m][n][r] + bcol);
                    *reinterpret_cast<bf16x4*>(
                        &oVt[((size_t)(b_ * H + h_) * DH + dh) * S + s_]) = o;
                }
            }
        } else {
            const float* bs = which == 0 ? b0 : b1;
            unsigned short* op = which == 0 ? oQ : oK;
            const float scale = which == 0 ? 0.125f : 1.0f;
            #pragma unroll
            for (int m = 0; m < 4; ++m)
                #pragma unroll
                for (int n = 0; n < 4; ++n) {
                    const int nn = (n0 + wc * 64 + n * 16 + lo) & 1023;
                    const float bcol = bs[nn];
                    const int h_ = nn >> 6, dh = nn & 63;
                    #pragma unroll
                    for (int r = 0; r < 4; ++r) {
                        const int row = m0 + wr * 64 + m * 16 + hi * 4 + r;
                        const int b_ = row >> 11, s_ = row & (S - 1);
                        op[(((size_t)(b_ * H + h_) * S) + s_) * DH + dh] =
                            f2bf((acc[m][n][r] + bcol) * scale);
                    }
                }
        }
    } else {
        #pragma unroll
        for (int m = 0; m < 4; ++m)
            #pragma unroll
            for (int n = 0; n < 4; ++n) {
                const int col = n0 + wc * 64 + n * 16 + lo;
                const float bcol = b0[col];
                #pragma unroll
                for (int r = 0; r < 4; ++r) {
                    const int row = m0 + wr * 64 + m * 16 + hi * 4 + r;
                    oF[(size_t)row * D + col] = acc[m][n][r] + bcol;
                }
            }
    }
}

// ---------------------------------------------------------------------------
// Fused attention: per block, sweep 1 computes per-row 1/sumexp entirely in
// registers (m=0; logits O(10), exp never overflows fp32); sweep 2 recomputes
// QK^T, writes normalized P (dbuf LDS stage -> coalesced 4-row x 256B
// nontemporal stores) and accumulates PV. No device-wide barrier between
// the phases: resident blocks in different sweeps overlap compute vs stores.
// ---------------------------------------------------------------------------
__global__ __launch_bounds__(256) void attn_fused(
    const unsigned short* __restrict__ Q, const unsigned short* __restrict__ K,
    const unsigned short* __restrict__ Vt, float* __restrict__ P,
    unsigned short* __restrict__ ctxb)
{
    __shared__ __align__(16) float Pf[2][4][16][68];
    const int bh = blockIdx.x;
    const int qt = (S / 64 - 1) - blockIdx.y;
    const int t = threadIdx.x, lane = t & 63, w = t >> 6;
    const int lo = lane & 15, hi = lane >> 4;
    const int q0 = qt * 64 + w * 16;
    const unsigned short* Qb = Q + (size_t)bh * S * DH;
    const unsigned short* Kb = K + (size_t)bh * S * DH;
    const unsigned short* Vb = Vt + (size_t)bh * DH * S;
    float* Pb = P + (size_t)bh * S * S;

    bf16x8 aq[2];
    #pragma unroll
    for (int kk = 0; kk < 2; ++kk)
        aq[kk] = *reinterpret_cast<const bf16x8*>(&Qb[(size_t)(q0 + lo) * DH + kk * 32 + hi * 8]);

    // ---- sweep 1: row sums (registers only)
    float li[4];
    {
        float rsum[4] = {0.f, 0.f, 0.f, 0.f};
        for (int jt = 0; jt <= qt; ++jt) {
            f32x4 acc[4] = {};
            #pragma unroll
            for (int kk = 0; kk < 2; ++kk)
                #pragma unroll
                for (int n = 0; n < 4; ++n) {
                    bf16x8 bk = *reinterpret_cast<const bf16x8*>(
                        &Kb[(size_t)(jt * 64 + n * 16 + lo) * DH + kk * 32 + hi * 8]);
                    acc[n] = __builtin_amdgcn_mfma_f32_16x16x32_bf16(aq[kk], bk, acc[n], 0, 0, 0);
                }
            const bool diag = (jt == qt);
            #pragma unroll
            for (int n = 0; n < 4; ++n) {
                const int j = jt * 64 + n * 16 + lo;
                #pragma unroll
                for (int r = 0; r < 4; ++r) {
                    const float e = __expf(acc[n][r]);
                    rsum[r] += (diag && j > q0 + hi * 4 + r) ? 0.f : e;
                }
            }
        }
        #pragma unroll
        for (int r = 0; r < 4; ++r) {
            #pragma unroll
            for (int off = 1; off < 16; off <<= 1) rsum[r] += __shfl_xor(rsum[r], off);
            li[r] = 1.0f / rsum[r];      // every lane holds its (hi,r) row's sum
        }
    }

    // ---- sweep 2: normalized P + PV context
    f32x4 actx[4] = {};

    for (int jt = 0; jt <= qt; ++jt) {
        float (*pf)[68] = Pf[jt & 1][w];
        f32x4 acc[4] = {};
        #pragma unroll
        for (int kk = 0; kk < 2; ++kk)
            #pragma unroll
            for (int n = 0; n < 4; ++n) {
                bf16x8 bk = *reinterpret_cast<const bf16x8*>(
                    &Kb[(size_t)(jt * 64 + n * 16 + lo) * DH + kk * 32 + hi * 8]);
                acc[n] = __builtin_amdgcn_mfma_f32_16x16x32_bf16(aq[kk], bk, acc[n], 0, 0, 0);
            }
        const bool diag = (jt == qt);
        #pragma unroll
        for (int n = 0; n < 4; ++n) {
            const int j = jt * 64 + n * 16 + lo;
            #pragma unroll
            for (int r = 0; r < 4; ++r) {
                const int qrow = q0 + hi * 4 + r;
                float p = __expf(acc[n][r]) * li[r];
                p = (diag && j > qrow) ? 0.f : p;
                pf[hi * 4 + r][n * 16 + lo] = p;
            }
        }
        // coalesced nontemporal f32x4 stores of the 16x64 fp32 tile
        #pragma unroll
        for (int i2 = 0; i2 < 4; ++i2) {
            const int row = i2 * 4 + hi;
            f32x4 v = *reinterpret_cast<const f32x4*>(&pf[row][lo * 4]);
            __builtin_nontemporal_store(
                v, reinterpret_cast<f32x4*>(&Pb[(size_t)(q0 + row) * S + jt * 64 + lo * 4]));
        }
        // PV: A-frag rebuilt from LDS fp32 (row=lo, k=kk*32+hi*8..+8)
        #pragma unroll
        for (int kk = 0; kk < 2; ++kk) {
            const float* src = &pf[lo][kk * 32 + hi * 8];
            float4 f0 = *reinterpret_cast<const float4*>(src);
            float4 f1 = *reinterpret_cast<const float4*>(src + 4);
            bf16x8 pa;
            pa[0] = f2bf(f0.x); pa[1] = f2bf(f0.y); pa[2] = f2bf(f0.z); pa[3] = f2bf(f0.w);
            pa[4] = f2bf(f1.x); pa[5] = f2bf(f1.y); pa[6] = f2bf(f1.z); pa[7] = f2bf(f1.w);
            #pragma unroll
            for (int n2 = 0; n2 < 4; ++n2) {
                bf16x8 bv = *reinterpret_cast<const bf16x8*>(
                    &Vb[(size_t)(n2 * 16 + lo) * S + jt * 64 + kk * 32 + hi * 8]);
                actx[n2] = __builtin_amdgcn_mfma_f32_16x16x32_bf16(pa, bv, actx[n2], 0, 0, 0);
            }
        }
    }

    // zero-fill strictly-upper tiles of P
    const f32x4 z = {0.f, 0.f, 0.f, 0.f};
    for (int jt = qt + 1; jt < S / 64; ++jt)
        #pragma unroll
        for (int rr = 0; rr < 4; ++rr) {
            const int qrow = q0 + rr * 4 + hi;
            __builtin_nontemporal_store(
                z, reinterpret_cast<f32x4*>(&Pb[(size_t)qrow * S + jt * 64 + lo * 4]));
        }

    // ctx -> merged-head bf16 [b*S+q][h*64+dh]
    const int b_ = bh >> 4, h_ = bh & 15;
    #pragma unroll
    for (int n2 = 0; n2 < 4; ++n2)
        #pragma unroll
        for (int r = 0; r < 4; ++r) {
            const int qg = q0 + hi * 4 + r;
            ctxb[((size_t)(b_ * S + qg)) * D + h_ * 64 + n2 * 16 + lo] = f2bf(actx[n2][r]);
        }
}

}  // namespace

extern "C" void kernel_launch(void* const* d_in, const int* in_sizes, int n_in,
                              void* d_out, int out_size, void* d_ws, size_t ws_size,
                              hipStream_t stream) {
    const float* x  = (const float*)d_in[0];
    const float* Wq = (const float*)d_in[2];
    const float* bq = (const float*)d_in[3];
    const float* Wk = (const float*)d_in[4];
    const float* bk = (const float*)d_in[5];
    const float* Wv = (const float*)d_in[6];
    const float* bv = (const float*)d_in[7];
    const float* Wo = (const float*)d_in[8];
    const float* bo = (const float*)d_in[9];

    float* out = (float*)d_out;
    float* P   = out + (size_t)M * D;

    char* ws = (char*)d_ws;
    const size_t MB = 1u << 20;
    unsigned short* xb    = (unsigned short*)(ws);            // 8 MB
    unsigned short* WtAll = (unsigned short*)(ws + 8 * MB);   // 8 MB  [Wq|Wk|Wv|Wo] transposed
    unsigned short* Qb    = (unsigned short*)(ws + 16 * MB);  // 8 MB
    unsigned short* Kb    = (unsigned short*)(ws + 24 * MB);  // 8 MB
    unsigned short* Vtb   = (unsigned short*)(ws + 32 * MB);  // 8 MB  [bh][dh][s]
    unsigned short* ctxb  = (unsigned short*)(ws + 40 * MB);  // 8 MB

    const dim3 blk(256);

    pack_x<<<dim3(M * D / (256 * 8)), blk, 0, stream>>>(x, xb);
    transpose_w4<<<dim3(16, 16, 4), blk, 0, stream>>>(Wq, Wk, Wv, Wo, WtAll);

    // fused QKV projection: N = 3072; V written directly transposed
    mfma_gemm<0><<<dim3(24, M / 128), blk, 0, stream>>>(
        xb, WtAll, bq, bk, bv, Qb, Kb, Vtb, nullptr);

    // fused attention: rowsum (sweep 1, in-register) + P + PV (sweep 2)
    attn_fused<<<dim3(B * H, S / 64), blk, 0, stream>>>(Qb, Kb, Vtb, P, ctxb);

    // output projection
    mfma_gemm<1><<<dim3(8, M / 128), blk, 0, stream>>>(
        ctxb, WtAll + (size_t)3 * D * D, bo, nullptr, nullptr,
        nullptr, nullptr, nullptr, out);
}

// Round 10
// 312.307 us; speedup vs baseline: 1.4037x; 1.0017x over previous
//
#include <hip/hip_runtime.h>
#include <cstdint>

namespace {

typedef __attribute__((ext_vector_type(8))) short bf16x8;
typedef __attribute__((ext_vector_type(4))) short bf16x4;
typedef __attribute__((ext_vector_type(4))) float f32x4;

constexpr int D  = 1024;
constexpr int H  = 16;
constexpr int DH = 64;
constexpr int B  = 2;
constexpr int S  = 2048;
constexpr int M  = B * S;          // 4096
// 1/sqrt(64) * log2(e): QK^T logits land pre-scaled for exp2
constexpr float SCALE_Q = 0.125f * 1.4426950408889634f;

__device__ inline unsigned short f2bf(float f) {
    union { float f; uint32_t u; } v{f};
    return (unsigned short)((v.u + 0x7fffu + ((v.u >> 16) & 1u)) >> 16);
}

__device__ inline void gload16(const void* g, void* l) {
    __builtin_amdgcn_global_load_lds(
        (const __attribute__((address_space(1))) void*)g,
        (__attribute__((address_space(3))) void*)l, 16, 0, 0);
}

// ---------------------------------------------------------------------------
// x [4096,1024] f32 -> bf16
// ---------------------------------------------------------------------------
__global__ __launch_bounds__(256) void pack_x(const float* __restrict__ x,
                                              unsigned short* __restrict__ xb) {
    const int i = (blockIdx.x * 256 + threadIdx.x) * 8;
    float4 a = *reinterpret_cast<const float4*>(&x[i]);
    float4 b = *reinterpret_cast<const float4*>(&x[i + 4]);
    bf16x8 o;
    o[0] = f2bf(a.x); o[1] = f2bf(a.y); o[2] = f2bf(a.z); o[3] = f2bf(a.w);
    o[4] = f2bf(b.x); o[5] = f2bf(b.y); o[6] = f2bf(b.z); o[7] = f2bf(b.w);
    *reinterpret_cast<bf16x8*>(&xb[i]) = o;
}

// ---------------------------------------------------------------------------
// 4 weight matrices [1024 k][1024 n] f32 -> WtAll bf16 [4][n][k]
// ---------------------------------------------------------------------------
__global__ __launch_bounds__(256) void transpose_w4(
    const float* __restrict__ W0, const float* __restrict__ W1,
    const float* __restrict__ W2, const float* __restrict__ W3,
    unsigned short* __restrict__ WtAll)
{
    __shared__ unsigned short T[64][72];
    const int z = blockIdx.z;
    const float* W = z == 0 ? W0 : (z == 1 ? W1 : (z == 2 ? W2 : W3));
    unsigned short* Wt = WtAll + (size_t)z * D * D;
    const int n0 = blockIdx.x * 64, k0 = blockIdx.y * 64;
    const int t = threadIdx.x;
    #pragma unroll
    for (int i = 0; i < 16; ++i) {
        int idx = i * 256 + t, r = idx >> 6, c = idx & 63;
        T[r][c] = f2bf(W[(size_t)(k0 + r) * D + n0 + c]);
    }
    __syncthreads();
    #pragma unroll
    for (int i = 0; i < 16; ++i) {
        int idx = i * 256 + t, r = idx >> 6, c = idx & 63;
        Wt[(size_t)(n0 + r) * D + k0 + c] = T[c][r];
    }
}

// ---------------------------------------------------------------------------
// MFMA GEMM, m97 structure: global_load_lds(16B) + XOR-swizzled linear LDS.
// C[M,N] = A[M,K] @ Bt[N,K]^T + bias.  128x128 tile, BK=64, 4 waves (2x2).
// MODE 0: fused QKV (N=3072): Q (scaled SCALE_Q incl. log2e), K -> split-head
//         bf16; V -> Vt[bh][dh][s] bf16 DIRECTLY (transpose in epilogue).
// MODE 1: fp32 row-major out (final projection, N=1024).
// ---------------------------------------------------------------------------
template <int MODE>
__global__ __launch_bounds__(256) void mfma_gemm(
    const unsigned short* __restrict__ A, const unsigned short* __restrict__ Bt,
    const float* __restrict__ b0, const float* __restrict__ b1,
    const float* __restrict__ b2,
    unsigned short* __restrict__ oQ, unsigned short* __restrict__ oK,
    unsigned short* __restrict__ oVt, float* __restrict__ oF)
{
    __shared__ __align__(16) unsigned short As[128 * 64];
    __shared__ __align__(16) unsigned short Bs[128 * 64];
    const int t = threadIdx.x;
    const int lane = t & 63, w = t >> 6;
    const int wr = w >> 1, wc = w & 1;
    const int lo = lane & 15, hi = lane >> 4;
    const int m0 = blockIdx.y * 128, n0 = blockIdx.x * 128;

    f32x4 acc[4][4] = {};

    for (int k0 = 0; k0 < D; k0 += 64) {
        #pragma unroll
        for (int i = 0; i < 4; ++i) {
            const int row = i * 32 + w * 8 + (lane >> 3);
            const int gcol = ((lane & 7) * 8) ^ ((row & 7) * 8);  // src pre-swizzle
            gload16(&A[(size_t)(m0 + row) * D + k0 + gcol], &As[i * 2048 + w * 512]);
            gload16(&Bt[(size_t)(n0 + row) * D + k0 + gcol], &Bs[i * 2048 + w * 512]);
        }
        __syncthreads();
        #pragma unroll
        for (int kk = 0; kk < 2; ++kk) {
            bf16x8 a[4], b[4];
            #pragma unroll
            for (int m = 0; m < 4; ++m) {
                const int row = wr * 64 + m * 16 + lo;
                a[m] = *reinterpret_cast<const bf16x8*>(
                    &As[row * 64 + ((kk * 32 + hi * 8) ^ ((row & 7) * 8))]);
            }
            #pragma unroll
            for (int n = 0; n < 4; ++n) {
                const int row = wc * 64 + n * 16 + lo;
                b[n] = *reinterpret_cast<const bf16x8*>(
                    &Bs[row * 64 + ((kk * 32 + hi * 8) ^ ((row & 7) * 8))]);
            }
            #pragma unroll
            for (int m = 0; m < 4; ++m)
                #pragma unroll
                for (int n = 0; n < 4; ++n)
                    acc[m][n] = __builtin_amdgcn_mfma_f32_16x16x32_bf16(a[m], b[n], acc[m][n], 0, 0, 0);
        }
        __syncthreads();
    }

    // acc[m][n][r]: row = m0+wr*64+m*16+hi*4+r, col = n0+wc*64+n*16+lo
    if (MODE == 0) {
        const int which = n0 >> 10;                 // uniform per block
        if (which == 2) {
            // V: write Vt[bh][dh][s] directly; 4 consecutive s per lane -> bf16x4
            #pragma unroll
            for (int m = 0; m < 4; ++m) {
                const int row0 = m0 + wr * 64 + m * 16 + hi * 4;
                const int b_ = row0 >> 11, s_ = row0 & (S - 1);
                #pragma unroll
                for (int n = 0; n < 4; ++n) {
                    const int nn = (n0 + wc * 64 + n * 16 + lo) & 1023;
                    const int h_ = nn >> 6, dh = nn & 63;
                    const float bcol = b2[nn];
                    bf16x4 o;
                    #pragma unroll
                    for (int r = 0; r < 4; ++r) o[r] = (short)f2bf(acc[m][n][r] + bcol);
                    *reinterpret_cast<bf16x4*>(
                        &oVt[((size_t)(b_ * H + h_) * DH + dh) * S + s_]) = o;
                }
            }
        } else {
            const float* bs = which == 0 ? b0 : b1;
            unsigned short* op = which == 0 ? oQ : oK;
            const float scale = which == 0 ? SCALE_Q : 1.0f;
            #pragma unroll
            for (int m = 0; m < 4; ++m)
                #pragma unroll
                for (int n = 0; n < 4; ++n) {
                    const int nn = (n0 + wc * 64 + n * 16 + lo) & 1023;
                    const float bcol = bs[nn];
                    const int h_ = nn >> 6, dh = nn & 63;
                    #pragma unroll
                    for (int r = 0; r < 4; ++r) {
                        const int row = m0 + wr * 64 + m * 16 + hi * 4 + r;
                        const int b_ = row >> 11, s_ = row & (S - 1);
                        op[(((size_t)(b_ * H + h_) * S) + s_) * DH + dh] =
                            f2bf((acc[m][n][r] + bcol) * scale);
                    }
                }
        }
    } else {
        #pragma unroll
        for (int m = 0; m < 4; ++m)
            #pragma unroll
            for (int n = 0; n < 4; ++n) {
                const int col = n0 + wc * 64 + n * 16 + lo;
                const float bcol = b0[col];
                #pragma unroll
                for (int r = 0; r < 4; ++r) {
                    const int row = m0 + wr * 64 + m * 16 + hi * 4 + r;
                    oF[(size_t)row * D + col] = acc[m][n][r] + bcol;
                }
            }
    }
}

// ---------------------------------------------------------------------------
// Fused attention (Q pre-scaled by log2e -> exp2f; diag tile peeled so the
// main jt loops are mask-free). Sweep 1: row 1/sumexp in registers.
// Sweep 2: recompute QK^T, normalized P via dbuf LDS stage -> coalesced
// 4-row x 256B nontemporal stores, PV from same LDS tile.
// ---------------------------------------------------------------------------
__global__ __launch_bounds__(256) void attn_fused(
    const unsigned short* __restrict__ Q, const unsigned short* __restrict__ K,
    const unsigned short* __restrict__ Vt, float* __restrict__ P,
    unsigned short* __restrict__ ctxb)
{
    __shared__ __align__(16) float Pf[2][4][16][68];
    const int bh = blockIdx.x;
    const int qt = (S / 64 - 1) - blockIdx.y;
    const int t = threadIdx.x, lane = t & 63, w = t >> 6;
    const int lo = lane & 15, hi = lane >> 4;
    const int q0 = qt * 64 + w * 16;
    const unsigned short* Qb = Q + (size_t)bh * S * DH;
    const unsigned short* Kb = K + (size_t)bh * S * DH;
    const unsigned short* Vb = Vt + (size_t)bh * DH * S;
    float* Pb = P + (size_t)bh * S * S;

    bf16x8 aq[2];
    #pragma unroll
    for (int kk = 0; kk < 2; ++kk)
        aq[kk] = *reinterpret_cast<const bf16x8*>(&Qb[(size_t)(q0 + lo) * DH + kk * 32 + hi * 8]);

    // ---- sweep 1: row sums (registers only); diag tile peeled
    float li[4];
    {
        float rsum[4] = {0.f, 0.f, 0.f, 0.f};
        for (int jt = 0; jt < qt; ++jt) {         // mask-free main loop
            f32x4 acc[4] = {};
            #pragma unroll
            for (int kk = 0; kk < 2; ++kk)
                #pragma unroll
                for (int n = 0; n < 4; ++n) {
                    bf16x8 bk = *reinterpret_cast<const bf16x8*>(
                        &Kb[(size_t)(jt * 64 + n * 16 + lo) * DH + kk * 32 + hi * 8]);
                    acc[n] = __builtin_amdgcn_mfma_f32_16x16x32_bf16(aq[kk], bk, acc[n], 0, 0, 0);
                }
            #pragma unroll
            for (int n = 0; n < 4; ++n)
                #pragma unroll
                for (int r = 0; r < 4; ++r) rsum[r] += exp2f(acc[n][r]);
        }
        {   // diag tile (jt == qt), masked
            f32x4 acc[4] = {};
            #pragma unroll
            for (int kk = 0; kk < 2; ++kk)
                #pragma unroll
                for (int n = 0; n < 4; ++n) {
                    bf16x8 bk = *reinterpret_cast<const bf16x8*>(
                        &Kb[(size_t)(qt * 64 + n * 16 + lo) * DH + kk * 32 + hi * 8]);
                    acc[n] = __builtin_amdgcn_mfma_f32_16x16x32_bf16(aq[kk], bk, acc[n], 0, 0, 0);
                }
            #pragma unroll
            for (int n = 0; n < 4; ++n) {
                const int j = qt * 64 + n * 16 + lo;
                #pragma unroll
                for (int r = 0; r < 4; ++r) {
                    const float e = exp2f(acc[n][r]);
                    rsum[r] += (j > q0 + hi * 4 + r) ? 0.f : e;
                }
            }
        }
        #pragma unroll
        for (int r = 0; r < 4; ++r) {
            #pragma unroll
            for (int off = 1; off < 16; off <<= 1) rsum[r] += __shfl_xor(rsum[r], off);
            li[r] = 1.0f / rsum[r];      // every lane holds its (hi,r) row's sum
        }
    }

    // ---- sweep 2: normalized P + PV context; diag tile peeled
    f32x4 actx[4] = {};

    for (int jt = 0; jt <= qt; ++jt) {
        float (*pf)[68] = Pf[jt & 1][w];
        f32x4 acc[4] = {};
        #pragma unroll
        for (int kk = 0; kk < 2; ++kk)
            #pragma unroll
            for (int n = 0; n < 4; ++n) {
                bf16x8 bk = *reinterpret_cast<const bf16x8*>(
                    &Kb[(size_t)(jt * 64 + n * 16 + lo) * DH + kk * 32 + hi * 8]);
                acc[n] = __builtin_amdgcn_mfma_f32_16x16x32_bf16(aq[kk], bk, acc[n], 0, 0, 0);
            }
        if (jt < qt) {                            // mask-free path
            #pragma unroll
            for (int n = 0; n < 4; ++n)
                #pragma unroll
                for (int r = 0; r < 4; ++r)
                    pf[hi * 4 + r][n * 16 + lo] = exp2f(acc[n][r]) * li[r];
        } else {                                  // diag tile, masked
            #pragma unroll
            for (int n = 0; n < 4; ++n) {
                const int j = qt * 64 + n * 16 + lo;
                #pragma unroll
                for (int r = 0; r < 4; ++r) {
                    const int qrow = q0 + hi * 4 + r;
                    float p = exp2f(acc[n][r]) * li[r];
                    pf[hi * 4 + r][n * 16 + lo] = (j > qrow) ? 0.f : p;
                }
            }
        }
        // coalesced nontemporal f32x4 stores of the 16x64 fp32 tile
        #pragma unroll
        for (int i2 = 0; i2 < 4; ++i2) {
            const int row = i2 * 4 + hi;
            f32x4 v = *reinterpret_cast<const f32x4*>(&pf[row][lo * 4]);
            __builtin_nontemporal_store(
                v, reinterpret_cast<f32x4*>(&Pb[(size_t)(q0 + row) * S + jt * 64 + lo * 4]));
        }
        // PV: A-frag rebuilt from LDS fp32 (row=lo, k=kk*32+hi*8..+8)
        #pragma unroll
        for (int kk = 0; kk < 2; ++kk) {
            const float* src = &pf[lo][kk * 32 + hi * 8];
            float4 f0 = *reinterpret_cast<const float4*>(src);
            float4 f1 = *reinterpret_cast<const float4*>(src + 4);
            bf16x8 pa;
            pa[0] = f2bf(f0.x); pa[1] = f2bf(f0.y); pa[2] = f2bf(f0.z); pa[3] = f2bf(f0.w);
            pa[4] = f2bf(f1.x); pa[5] = f2bf(f1.y); pa[6] = f2bf(f1.z); pa[7] = f2bf(f1.w);
            #pragma unroll
            for (int n2 = 0; n2 < 4; ++n2) {
                bf16x8 bv = *reinterpret_cast<const bf16x8*>(
                    &Vb[(size_t)(n2 * 16 + lo) * S + jt * 64 + kk * 32 + hi * 8]);
                actx[n2] = __builtin_amdgcn_mfma_f32_16x16x32_bf16(pa, bv, actx[n2], 0, 0, 0);
            }
        }
    }

    // zero-fill strictly-upper tiles of P
    const f32x4 z = {0.f, 0.f, 0.f, 0.f};
    for (int jt = qt + 1; jt < S / 64; ++jt)
        #pragma unroll
        for (int rr = 0; rr < 4; ++rr) {
            const int qrow = q0 + rr * 4 + hi;
            __builtin_nontemporal_store(
                z, reinterpret_cast<f32x4*>(&Pb[(size_t)qrow * S + jt * 64 + lo * 4]));
        }

    // ctx -> merged-head bf16 [b*S+q][h*64+dh]
    const int b_ = bh >> 4, h_ = bh & 15;
    #pragma unroll
    for (int n2 = 0; n2 < 4; ++n2)
        #pragma unroll
        for (int r = 0; r < 4; ++r) {
            const int qg = q0 + hi * 4 + r;
            ctxb[((size_t)(b_ * S + qg)) * D + h_ * 64 + n2 * 16 + lo] = f2bf(actx[n2][r]);
        }
}

}  // namespace

extern "C" void kernel_launch(void* const* d_in, const int* in_sizes, int n_in,
                              void* d_out, int out_size, void* d_ws, size_t ws_size,
                              hipStream_t stream) {
    const float* x  = (const float*)d_in[0];
    const float* Wq = (const float*)d_in[2];
    const float* bq = (const float*)d_in[3];
    const float* Wk = (const float*)d_in[4];
    const float* bk = (const float*)d_in[5];
    const float* Wv = (const float*)d_in[6];
    const float* bv = (const float*)d_in[7];
    const float* Wo = (const float*)d_in[8];
    const float* bo = (const float*)d_in[9];

    float* out = (float*)d_out;
    float* P   = out + (size_t)M * D;

    char* ws = (char*)d_ws;
    const size_t MB = 1u << 20;
    unsigned short* xb    = (unsigned short*)(ws);            // 8 MB
    unsigned short* WtAll = (unsigned short*)(ws + 8 * MB);   // 8 MB  [Wq|Wk|Wv|Wo] transposed
    unsigned short* Qb    = (unsigned short*)(ws + 16 * MB);  // 8 MB
    unsigned short* Kb    = (unsigned short*)(ws + 24 * MB);  // 8 MB
    unsigned short* Vtb   = (unsigned short*)(ws + 32 * MB);  // 8 MB  [bh][dh][s]
    unsigned short* ctxb  = (unsigned short*)(ws + 40 * MB);  // 8 MB

    const dim3 blk(256);

    pack_x<<<dim3(M * D / (256 * 8)), blk, 0, stream>>>(x, xb);
    transpose_w4<<<dim3(16, 16, 4), blk, 0, stream>>>(Wq, Wk, Wv, Wo, WtAll);

    // fused QKV projection: N = 3072; V written directly transposed
    mfma_gemm<0><<<dim3(24, M / 128), blk, 0, stream>>>(
        xb, WtAll, bq, bk, bv, Qb, Kb, Vtb, nullptr);

    // fused attention: rowsum (sweep 1, in-register) + P + PV (sweep 2)
    attn_fused<<<dim3(B * H, S / 64), blk, 0, stream>>>(Qb, Kb, Vtb, P, ctxb);

    // output projection
    mfma_gemm<1><<<dim3(8, M / 128), blk, 0, stream>>>(
        ctxb, WtAll + (size_t)3 * D * D, bo, nullptr, nullptr,
        nullptr, nullptr, nullptr, out);
}